// Round 7
// baseline (538.320 us; speedup 1.0000x reference)
//
#include <hip/hip_runtime.h>

#define B_SZ   2
#define S_LEN  2048
#define D_DIM  1024
#define V_DIM  32000
#define NTOK   (B_SZ * S_LEN)   // 4096
#define NCYC   8
#define NPLANES 256
#define EPS_F  1.1920929e-07f

typedef float  f32x4  __attribute__((ext_vector_type(4)));
typedef __bf16 bf16x8 __attribute__((ext_vector_type(8)));

__device__ __forceinline__ unsigned short f32_to_bf16(float f) {
    unsigned int u = __builtin_bit_cast(unsigned int, f);
    u += 0x7fffu + ((u >> 16) & 1u);   // round-to-nearest-even
    return (unsigned short)(u >> 16);
}

__device__ __forceinline__ float4 mix3(float a, const float4& u, float b,
                                       const float4& v, float c, const float4& w) {
    return make_float4(a * u.x + b * v.x + c * w.x,
                       a * u.y + b * v.y + c * w.y,
                       a * u.z + b * v.z + c * w.z,
                       a * u.w + b * v.w + c * w.w);
}

// ============ per-cycle kernel: block owns tokens 4b..4b+3 =================
__global__ __launch_bounds__(256) void k_cyc(
    int c,
    const int* __restrict__ tokens, const float* __restrict__ table,
    const float* __restrict__ xin, float* __restrict__ xout,
    const float* __restrict__ angles, const float* __restrict__ scales,
    const float* __restrict__ shifts, const float* __restrict__ normw,
    const float* __restrict__ mixw, const float* __restrict__ outnw,
    unsigned short* __restrict__ xbf,
    const int* __restrict__ pi, const int* __restrict__ pj,
    const float* __restrict__ lmhead, unsigned short* __restrict__ wbf)
{
    __shared__ float lx[4][D_DIM];
    __shared__ float red[4][4];   // [wave][token]
    const int b = blockIdx.x, tid = threadIdx.x;
    const int wv = tid >> 6, ln = tid & 63;
    const int t0 = b << 2;
    const int s0 = t0 & (S_LEN - 1);

    float4 row[4];
    float4 hl = make_float4(0.f, 0.f, 0.f, 0.f);
    float4 hr = make_float4(0.f, 0.f, 0.f, 0.f);
    if (c == 0) {
        #pragma unroll
        for (int i = 0; i < 4; ++i) {
            const int tok = tokens[t0 + i];
            row[i] = ((const float4*)(table + (size_t)tok * D_DIM))[tid];
        }
        if (s0 > 0) {
            const int tok = tokens[t0 - 1];
            hl = ((const float4*)(table + (size_t)tok * D_DIM))[tid];
        }
        if (s0 + 4 < S_LEN) {
            const int tok = tokens[t0 + 4];
            hr = ((const float4*)(table + (size_t)tok * D_DIM))[tid];
        }
    } else {
        #pragma unroll
        for (int i = 0; i < 4; ++i)
            row[i] = ((const float4*)(xin + (size_t)(t0 + i) * D_DIM))[tid];
        if (s0 > 0)
            hl = ((const float4*)(xin + (size_t)(t0 - 1) * D_DIM))[tid];
        if (s0 + 4 < S_LEN)
            hr = ((const float4*)(xin + (size_t)(t0 + 4) * D_DIM))[tid];
    }
    const float mw0 = mixw[0], mw1 = mixw[1], mw2 = mixw[2];

    float4 m[4];
    m[0] = mix3(mw0, hl,     mw1, row[0], mw2, row[1]);
    m[1] = mix3(mw0, row[0], mw1, row[1], mw2, row[2]);
    m[2] = mix3(mw0, row[1], mw1, row[2], mw2, row[3]);
    m[3] = mix3(mw0, row[2], mw1, row[3], mw2, hr);
    #pragma unroll
    for (int i = 0; i < 4; ++i) ((float4*)lx[i])[tid] = m[i];
    __syncthreads();

    const int ip = pi[tid], jp = pj[tid];
    float sa, ca;
    sincosf(angles[tid], &sa, &ca);
    float xi[4], xj[4];
    #pragma unroll
    for (int i = 0; i < 4; ++i) { xi[i] = lx[i][ip]; xj[i] = lx[i][jp]; }
    #pragma unroll
    for (int i = 0; i < 4; ++i) {
        lx[i][ip] = xi[i] * ca - xj[i] * sa;
        lx[i][jp] = xi[i] * sa + xj[i] * ca;
    }
    __syncthreads();

    const float4 sc = ((const float4*)scales)[tid];
    const float4 sh = ((const float4*)shifts)[tid];
    const float4 nw = ((const float4*)normw)[tid];
    float4 r[4];
    float sum[4];
    #pragma unroll
    for (int i = 0; i < 4; ++i) {
        const float4 xn = ((const float4*)lx[i])[tid];
        const float a0 = xn.x * sc.x + sh.x;
        const float a1 = xn.y * sc.y + sh.y;
        const float a2 = xn.z * sc.z + sh.z;
        const float a3 = xn.w * sc.w + sh.w;
        r[i].x = a0 / (1.f + expf(-a0)) - m[i].x;
        r[i].y = a1 / (1.f + expf(-a1)) - m[i].y;
        r[i].z = a2 / (1.f + expf(-a2)) - m[i].z;
        r[i].w = a3 / (1.f + expf(-a3)) - m[i].w;
        sum[i] = r[i].x * r[i].x + r[i].y * r[i].y
               + r[i].z * r[i].z + r[i].w * r[i].w;
    }
    #pragma unroll
    for (int off = 32; off > 0; off >>= 1)
        #pragma unroll
        for (int i = 0; i < 4; ++i) sum[i] += __shfl_down(sum[i], off, 64);
    if (ln == 0) {
        red[wv][0] = sum[0]; red[wv][1] = sum[1];
        red[wv][2] = sum[2]; red[wv][3] = sum[3];
    }
    __syncthreads();
    #pragma unroll
    for (int i = 0; i < 4; ++i) {
        const float tot = red[0][i] + red[1][i] + red[2][i] + red[3][i];
        const float inv = rsqrtf(tot * (1.0f / D_DIM) + EPS_F);
        row[i].x = m[i].x + r[i].x * inv * nw.x;
        row[i].y = m[i].y + r[i].y * inv * nw.y;
        row[i].z = m[i].z + r[i].z * inv * nw.z;
        row[i].w = m[i].w + r[i].w * inv * nw.w;
    }

    if (c == 7) {
        __syncthreads();
        float fs[4];
        #pragma unroll
        for (int i = 0; i < 4; ++i)
            fs[i] = row[i].x * row[i].x + row[i].y * row[i].y
                  + row[i].z * row[i].z + row[i].w * row[i].w;
        #pragma unroll
        for (int off = 32; off > 0; off >>= 1)
            #pragma unroll
            for (int i = 0; i < 4; ++i) fs[i] += __shfl_down(fs[i], off, 64);
        if (ln == 0) {
            red[wv][0] = fs[0]; red[wv][1] = fs[1];
            red[wv][2] = fs[2]; red[wv][3] = fs[3];
        }
        __syncthreads();
        const float4 w = ((const float4*)outnw)[tid];
        #pragma unroll
        for (int i = 0; i < 4; ++i) {
            const float tot = red[0][i] + red[1][i] + red[2][i] + red[3][i];
            const float inv = rsqrtf(tot * (1.0f / D_DIM) + EPS_F);
            const ushort4 o = make_ushort4(f32_to_bf16(row[i].x * inv * w.x),
                                           f32_to_bf16(row[i].y * inv * w.y),
                                           f32_to_bf16(row[i].z * inv * w.z),
                                           f32_to_bf16(row[i].w * inv * w.w));
            ((ushort4*)xbf)[(size_t)(t0 + i) * 256 + tid] = o;
        }
    } else {
        #pragma unroll
        for (int i = 0; i < 4; ++i)
            ((float4*)(xout + (size_t)(t0 + i) * D_DIM))[tid] = row[i];
    }

    // lm_head fp32->bf16 slice for this cycle
    {
        const int end = (c + 1) * 1024000;
        for (int i = c * 1024000 + b * 256 + tid; i < end; i += 262144) {
            const float4 v = ((const float4*)lmhead)[i];
            const ushort4 o = make_ushort4(f32_to_bf16(v.x), f32_to_bf16(v.y),
                                           f32_to_bf16(v.z), f32_to_bf16(v.w));
            ((ushort4*)wbf)[i] = o;
        }
    }
}

// ====== GEMM: 128x128 tile, BK=64, 4 waves, 2 blocks/CU (m97 structure) ====
// C[M,N] = A[M,K]*B[N,K]^T. Non-persistent: 8000 blocks (32 bm x 250 bn).
// Per K-step: stage next K-tile (8 x global_load_lds w=16) BEFORE reading
// current buf; 32 MFMA 16x16x32; one __syncthreads (compiler emits the
// vmcnt/lgkmcnt drain). The drain-0 stall + epilogue C-store drain are
// hidden by the SECOND resident block on the CU (independent vmcnt FIFO)
// -- that's the whole point of this round's change.
// LDS 64 KiB/block: 2 bufs x (A 128x64 + B 128x64) bf16, XOR-swizzled
// (col-group ^= row&7, pre-swizzled global source for linear gld_lds dest).
#define GLD_LDS(g, l)                                                          \
    __builtin_amdgcn_global_load_lds(                                          \
        (const __attribute__((address_space(1))) void*)(g),                    \
        (__attribute__((address_space(3))) void*)(l), 16, 0, 0)

__global__ __launch_bounds__(256, 2) void k_gemm(
    const unsigned short* __restrict__ A,   // [NTOK, 1024] bf16 bits
    const unsigned short* __restrict__ Bw,  // [V, 1024]    bf16 bits
    float* __restrict__ C)                  // [NTOK, V]    fp32
{
    __shared__ __align__(16) unsigned short lds[2][16384];  // 64 KiB
    const int tid = threadIdx.x;
    const int wave = tid >> 6, lane = tid & 63;
    const int wm = wave >> 1, wn = wave & 1;
    const int lr = lane & 15, kg = lane >> 4;

    // XCD-chunked tile map: xcd owns [x*1000,(x+1)*1000); concurrent
    // same-XCD blocks have consecutive T -> share 2-3 B panels in L2.
    const int x  = blockIdx.x & 7;
    const int lb = blockIdx.x >> 3;
    const int T  = x * 1000 + lb;
    const int bm = T & 31, bn = T >> 5;

    // staging: call r covers rows r*32 + wave*8 + (lane>>3), colgrp lane&7
    const int srow = lane >> 3;               // 0..7 (== row & 7)
    const int scg  = lane & 7;
    const int scol = (scg ^ srow) * 8;        // pre-swizzled source col
    const unsigned short* gA = A  + (size_t)(bm * 128 + wave * 8 + srow) * 1024 + scol;
    const unsigned short* gB = Bw + (size_t)(bn * 128 + wave * 8 + srow) * 1024 + scol;

    // frag-read swizzled col offsets (row stride 64 elems = 128 B)
    const int sx = lane & 7;                  // == (frag row) & 7
    const int ka = ((kg ^ sx) * 8);           // k-half 0 (cols 0..31)
    const int kb = (((kg + 4) ^ sx) * 8);     // k-half 1 (cols 32..63)
    const int arow = wm * 64 + lr;
    const int brow = wn * 64 + lr;

    f32x4 acc[4][4];
    #pragma unroll
    for (int i = 0; i < 4; ++i)
        #pragma unroll
        for (int j = 0; j < 4; ++j) acc[i][j] = (f32x4){0.f, 0.f, 0.f, 0.f};
    bf16x8 af0[4], af1[4], bf0[4], bf1[4];

#define STAGE(BUF, KT) do { _Pragma("unroll")                                  \
    for (int r_ = 0; r_ < 4; ++r_) {                                           \
        GLD_LDS(gA + (size_t)r_ * 32 * 1024 + (size_t)(KT) * 64,               \
                &lds[BUF][r_ * 2048 + wave * 512]);                            \
        GLD_LDS(gB + (size_t)r_ * 32 * 1024 + (size_t)(KT) * 64,               \
                &lds[BUF][8192 + r_ * 2048 + wave * 512]);                     \
    } } while (0)

#define RDF(BUF) do { _Pragma("unroll")                                        \
    for (int q_ = 0; q_ < 4; ++q_) {                                           \
        af0[q_] = *(const bf16x8*)&lds[BUF][(arow + q_ * 16) * 64 + ka];       \
        af1[q_] = *(const bf16x8*)&lds[BUF][(arow + q_ * 16) * 64 + kb];       \
        bf0[q_] = *(const bf16x8*)&lds[BUF][8192 + (brow + q_ * 16) * 64 + ka];\
        bf1[q_] = *(const bf16x8*)&lds[BUF][8192 + (brow + q_ * 16) * 64 + kb];\
    } } while (0)

    STAGE(0, 0);
    __syncthreads();

    int cur = 0;
    for (int kt = 0; kt < 16; ++kt) {
        const int ktn = (kt < 15) ? kt + 1 : 15;   // last: redundant restage
        STAGE(cur ^ 1, ktn);
        RDF(cur);
        __builtin_amdgcn_s_setprio(1);
        #pragma unroll
        for (int mi = 0; mi < 4; ++mi)
            #pragma unroll
            for (int ni = 0; ni < 4; ++ni) {
                acc[mi][ni] = __builtin_amdgcn_mfma_f32_16x16x32_bf16(
                    af0[mi], bf0[ni], acc[mi][ni], 0, 0, 0);
                acc[mi][ni] = __builtin_amdgcn_mfma_f32_16x16x32_bf16(
                    af1[mi], bf1[ni], acc[mi][ni], 0, 0, 0);
            }
        __builtin_amdgcn_s_setprio(0);
        __syncthreads();
        cur ^= 1;
    }

    // epilogue: C row = bm*128 + wm*64 + mi*16 + kg*4 + reg,
    //           col = bn*128 + wn*64 + ni*16 + lr  (verified mapping)
    #pragma unroll
    for (int mi = 0; mi < 4; ++mi) {
        const size_t m0 = (size_t)(bm * 128 + wm * 64 + mi * 16 + kg * 4);
        #pragma unroll
        for (int ni = 0; ni < 4; ++ni) {
            const int n = bn * 128 + wn * 64 + ni * 16 + lr;
            float* cp = C + m0 * V_DIM + n;
            cp[0]                 = acc[mi][ni][0];
            cp[(size_t)V_DIM]     = acc[mi][ni][1];
            cp[(size_t)2 * V_DIM] = acc[mi][ni][2];
            cp[(size_t)3 * V_DIM] = acc[mi][ni][3];
        }
    }
#undef STAGE
#undef RDF
}

extern "C" void kernel_launch(void* const* d_in, const int* in_sizes, int n_in,
                              void* d_out, int out_size, void* d_ws, size_t ws_size,
                              hipStream_t stream)
{
    const int*   tokens = (const int*)  d_in[0];
    const float* embedw = (const float*)d_in[1];
    const float* angles = (const float*)d_in[2];
    const float* scales = (const float*)d_in[3];
    const float* shifts = (const float*)d_in[4];
    const float* normw  = (const float*)d_in[5];
    const float* mixw   = (const float*)d_in[6];
    const float* outnw  = (const float*)d_in[7];
    const float* lmhead = (const float*)d_in[8];
    const int*   pi_all = (const int*)  d_in[9];
    const int*   pj_all = (const int*)  d_in[10];
    float* out = (float*)d_out;

    float* xa = (float*)d_ws;
    float* xb = xa + (size_t)NTOK * D_DIM;
    unsigned short* xbf = (unsigned short*)(xb + (size_t)NTOK * D_DIM);
    unsigned short* wbf = xbf + (size_t)NTOK * D_DIM;

    for (int c = 0; c < NCYC; ++c) {
        const float* xin = (c & 1) ? xb : xa;
        float* xout = (c & 1) ? xa : xb;
        k_cyc<<<NTOK / 4, 256, 0, stream>>>(c, tokens, embedw, xin, xout,
            angles + c * NPLANES, scales + c * D_DIM, shifts + c * D_DIM,
            normw + c * D_DIM, mixw, outnw, xbf,
            pi_all + c * NPLANES, pj_all + c * NPLANES, lmhead, wbf);
    }

    k_gemm<<<8000, 256, 0, stream>>>(xbf, wbf, out);
}

// Round 8
// 467.851 us; speedup vs baseline: 1.1506x; 1.1506x over previous
//
#include <hip/hip_runtime.h>

#define B_SZ   2
#define S_LEN  2048
#define D_DIM  1024
#define V_DIM  32000
#define NTOK   (B_SZ * S_LEN)   // 4096
#define NCYC   8
#define NPLANES 256
#define EPS_F  1.1920929e-07f
#define NTILE  2000             // 16 bm x 125 bn

typedef float  f32x4  __attribute__((ext_vector_type(4)));
typedef __bf16 bf16x8 __attribute__((ext_vector_type(8)));

__device__ __forceinline__ unsigned short f32_to_bf16(float f) {
    unsigned int u = __builtin_bit_cast(unsigned int, f);
    u += 0x7fffu + ((u >> 16) & 1u);   // round-to-nearest-even
    return (unsigned short)(u >> 16);
}

// ============ fused chain: embed + 8 cycles + final norm + lm_head cvt =====
// One launch, 256 blocks x 512 thr. Block owns tokens [t0, t0+16); loads 32
// rows (8-halo each side) into LDS and runs ALL 8 cycles locally -- the
// valid range shrinks by 1 token/side/cycle (halo redundancy), no grid sync.
// Rows outside the sequence stay 0 (= reference's zero padding).
// Thread owns cols [2*tid, 2*tid+2). All range predicates are block-uniform.
__global__ __launch_bounds__(512, 2) void k_chain(
    const int* __restrict__ tokens, const float* __restrict__ table,
    const float* __restrict__ angles, const float* __restrict__ scales,
    const float* __restrict__ shifts, const float* __restrict__ normw,
    const float* __restrict__ mixw, const float* __restrict__ outnw,
    const int* __restrict__ pi_all, const int* __restrict__ pj_all,
    const float* __restrict__ lmhead,
    unsigned short* __restrict__ xbf, unsigned short* __restrict__ wbf)
{
    __shared__ float lx[32][D_DIM];   // 128 KiB
    __shared__ float red[8][32];
    const int blk = blockIdx.x, tid = threadIdx.x;
    const int wv = tid >> 6, ln = tid & 63;
    const int t0 = blk << 4;
    const int s0 = t0 & (S_LEN - 1);
    const int seqbase = t0 & ~(S_LEN - 1);
    const int c2 = tid << 1;

    const float mw0 = mixw[0], mw1 = mixw[1], mw2 = mixw[2];

    // ---- embed rows r=0..31 (s = s0-8+r); invalid rows stay 0 ----
    unsigned int svmask = 0;
    #pragma unroll
    for (int r = 0; r < 32; ++r) {
        const int s = s0 - 8 + r;
        const bool sv = (s >= 0) && (s < S_LEN);
        if (sv) svmask |= (1u << r);
        float2 v = make_float2(0.f, 0.f);
        if (sv) {
            const int tok = tokens[seqbase + s];
            v = *(const float2*)(table + (size_t)tok * D_DIM + c2);
        }
        lx[r][c2] = v.x; lx[r][c2 + 1] = v.y;
    }
    __syncthreads();

    float2 mreg[31], rres[31];   // indices 1..30, statically indexed

    for (int c = 0; c < NCYC; ++c) {
        const float2 sc = *(const float2*)(scales + c * D_DIM + c2);
        const float2 sh = *(const float2*)(shifts + c * D_DIM + c2);
        const float2 nw = *(const float2*)(normw  + c * D_DIM + c2);
        const int p    = tid & 255;
        const int half = tid >> 8;
        const int ip = pi_all[c * NPLANES + p];
        const int jp = pj_all[c * NPLANES + p];
        float sa, ca;
        sincosf(angles[c * NPLANES + p], &sa, &ca);

        // ---- temporal mix: read phase (prev-cycle values) ----
        #pragma unroll
        for (int r = 1; r <= 30; ++r) {
            if (r >= c + 1 && r < 31 - c && ((svmask >> r) & 1)) {
                const float2 a = make_float2(lx[r - 1][c2], lx[r - 1][c2 + 1]);
                const float2 b = make_float2(lx[r][c2],     lx[r][c2 + 1]);
                const float2 d = make_float2(lx[r + 1][c2], lx[r + 1][c2 + 1]);
                mreg[r].x = mw0 * a.x + mw1 * b.x + mw2 * d.x;
                mreg[r].y = mw0 * a.y + mw1 * b.y + mw2 * d.y;
            }
        }
        __syncthreads();
        // ---- mix: write phase ----
        #pragma unroll
        for (int r = 1; r <= 30; ++r) {
            if (r >= c + 1 && r < 31 - c && ((svmask >> r) & 1)) {
                lx[r][c2] = mreg[r].x; lx[r][c2 + 1] = mreg[r].y;
            }
        }
        __syncthreads();
        // ---- Givens rotation (disjoint planes; same-thread read+write) ----
        #pragma unroll
        for (int r = 1; r <= 30; ++r) {
            if (r >= c + 1 && r < 31 - c && ((svmask >> r) & 1) && (r & 1) == half) {
                const float xi = lx[r][ip], xj = lx[r][jp];
                lx[r][ip] = xi * ca - xj * sa;
                lx[r][jp] = xi * sa + xj * ca;
            }
        }
        __syncthreads();
        // ---- scale/shift + SiLU residual; per-row partial sums ----
        #pragma unroll
        for (int r = 1; r <= 30; ++r) {
            if (r >= c + 1 && r < 31 - c && ((svmask >> r) & 1)) {
                const float v0 = lx[r][c2], v1 = lx[r][c2 + 1];
                const float a0 = v0 * sc.x + sh.x;
                const float a1 = v1 * sc.y + sh.y;
                rres[r].x = a0 / (1.f + expf(-a0)) - mreg[r].x;
                rres[r].y = a1 / (1.f + expf(-a1)) - mreg[r].y;
                float pp = rres[r].x * rres[r].x + rres[r].y * rres[r].y;
                #pragma unroll
                for (int off = 32; off > 0; off >>= 1)
                    pp += __shfl_down(pp, off, 64);
                if (ln == 0) red[wv][r] = pp;
            }
        }
        __syncthreads();
        // ---- norm + writeback ----
        #pragma unroll
        for (int r = 1; r <= 30; ++r) {
            if (r >= c + 1 && r < 31 - c && ((svmask >> r) & 1)) {
                const float tot = red[0][r] + red[1][r] + red[2][r] + red[3][r]
                                + red[4][r] + red[5][r] + red[6][r] + red[7][r];
                const float inv = rsqrtf(tot * (1.0f / D_DIM) + EPS_F);
                lx[r][c2]     = mreg[r].x + rres[r].x * inv * nw.x;
                lx[r][c2 + 1] = mreg[r].y + rres[r].y * inv * nw.y;
            }
        }
        __syncthreads();
    }

    // ---- final RMSNorm + bf16 cast for owned rows 8..23 ----
    const float2 ow = *(const float2*)(outnw + c2);
    #pragma unroll
    for (int r = 8; r < 24; ++r) {
        const float v0 = lx[r][c2], v1 = lx[r][c2 + 1];
        float pp = v0 * v0 + v1 * v1;
        #pragma unroll
        for (int off = 32; off > 0; off >>= 1)
            pp += __shfl_down(pp, off, 64);
        if (ln == 0) red[wv][r - 8] = pp;
    }
    __syncthreads();
    #pragma unroll
    for (int r = 8; r < 24; ++r) {
        const float tot = red[0][r - 8] + red[1][r - 8] + red[2][r - 8] + red[3][r - 8]
                        + red[4][r - 8] + red[5][r - 8] + red[6][r - 8] + red[7][r - 8];
        const float inv = rsqrtf(tot * (1.0f / D_DIM) + EPS_F);
        const float v0 = lx[r][c2], v1 = lx[r][c2 + 1];
        ushort2 o = make_ushort2(f32_to_bf16(v0 * inv * ow.x),
                                 f32_to_bf16(v1 * inv * ow.y));
        *(ushort2*)(xbf + (size_t)(t0 + r - 8) * D_DIM + c2) = o;
    }

    // ---- lm_head fp32 -> bf16 (grid-stride over 8.192M float4) ----
    for (int i = blk * 512 + tid; i < (V_DIM * D_DIM) / 4; i += 256 * 512) {
        const float4 v = ((const float4*)lmhead)[i];
        const ushort4 o = make_ushort4(f32_to_bf16(v.x), f32_to_bf16(v.y),
                                       f32_to_bf16(v.z), f32_to_bf16(v.w));
        ((ushort4*)wbf)[i] = o;
    }
}

// ====== persistent GEMM: 256x256 tile, BK=64, 8-phase, XCD-grouped tiles ===
// (unchanged from round 6 -- best measured: ~299 us)
#define GLD_LDS(g, l)                                                          \
    __builtin_amdgcn_global_load_lds(                                          \
        (const __attribute__((address_space(1))) void*)(g),                    \
        (__attribute__((address_space(3))) void*)(l), 16, 0, 0)

#define STAGE_A(BUF, H, KT, P) do {                                            \
    GLD_LDS((P) + (size_t)(H) * 131072 + (size_t)(KT) * 64,                    \
            &lds[(BUF) * 32768 + (H) * 8192 + wave * 1024]);                   \
    GLD_LDS((P) + (size_t)(H) * 131072 + 8192 + (size_t)(KT) * 64,             \
            &lds[(BUF) * 32768 + (H) * 8192 + wave * 1024 + 512]);             \
} while (0)

#define STAGE_B(BUF, H, KT, P) do {                                            \
    GLD_LDS((P) + (size_t)(H) * 131072 + (size_t)(KT) * 64,                    \
            &lds[16384 + (BUF) * 32768 + (H) * 8192 + wave * 1024]);           \
    GLD_LDS((P) + (size_t)(H) * 131072 + 8192 + (size_t)(KT) * 64,             \
            &lds[16384 + (BUF) * 32768 + (H) * 8192 + wave * 1024 + 512]);     \
} while (0)

#define RD_A(BUF, MIB) do { _Pragma("unroll")                                  \
    for (int q_ = 0; q_ < 4; ++q_) {                                           \
        afr[q_][0] = *(const bf16x8*)&lds[(BUF) * 32768 + aoff + ((MIB) + q_) * 1024 + kx0]; \
        afr[q_][1] = *(const bf16x8*)&lds[(BUF) * 32768 + aoff + ((MIB) + q_) * 1024 + kx1]; \
    } } while (0)

#define RD_B(BUF, NIB, DST) do { _Pragma("unroll")                             \
    for (int n_ = 0; n_ < 2; ++n_) {                                           \
        DST[n_][0] = *(const bf16x8*)&lds[(BUF) * 32768 + boff + ((NIB) + n_) * 1024 + kx0]; \
        DST[n_][1] = *(const bf16x8*)&lds[(BUF) * 32768 + boff + ((NIB) + n_) * 1024 + kx1]; \
    } } while (0)

#define MFMA16(MIB, NIB, BF) do {                                              \
    __builtin_amdgcn_s_setprio(1);                                             \
    _Pragma("unroll") for (int m_ = 0; m_ < 4; ++m_)                           \
    _Pragma("unroll") for (int n_ = 0; n_ < 2; ++n_) {                         \
        acc[(MIB) + m_][(NIB) + n_] = __builtin_amdgcn_mfma_f32_16x16x32_bf16( \
            afr[m_][0], BF[n_][0], acc[(MIB) + m_][(NIB) + n_], 0, 0, 0);      \
        acc[(MIB) + m_][(NIB) + n_] = __builtin_amdgcn_mfma_f32_16x16x32_bf16( \
            afr[m_][1], BF[n_][1], acc[(MIB) + m_][(NIB) + n_], 0, 0, 0);      \
    }                                                                          \
    __builtin_amdgcn_s_setprio(0); } while (0)

#define PH_SYNC() do { __builtin_amdgcn_s_barrier();                           \
    asm volatile("s_waitcnt lgkmcnt(0)" ::: "memory"); } while (0)
#define PH_END() do { asm volatile("" ::: "memory");                           \
    __builtin_amdgcn_s_barrier(); } while (0)
#define VMCNT4() asm volatile("s_waitcnt vmcnt(4)" ::: "memory")

__global__ __launch_bounds__(512, 2) void k_gemm(
    const unsigned short* __restrict__ A,   // [NTOK, 1024] bf16 bits
    const unsigned short* __restrict__ Bw,  // [V, 1024]    bf16 bits
    float* __restrict__ C)                  // [NTOK, V]    fp32
{
    __shared__ __align__(16) unsigned short lds[65536];   // 128 KiB
    const int tid = threadIdx.x;
    const int wave = tid >> 6, lane = tid & 63;
    const int wm = wave >> 2, wn = wave & 3;
    const int lr = lane & 15, kg = lane >> 4;

    const int xr  = (lane & 7) * 8;
    const int kx0 = (kg * 8) ^ xr;
    const int kx1 = (32 + kg * 8) ^ xr;
    const int aoff = (wm * 128 + lr) * 64;
    const int boff = 16384 + (wn * 64 + lr) * 64;

    const int srow = lane >> 3;
    const int scol = ((lane & 7) ^ srow) * 8;   // pre-swizzled source col
    const int soff = (wave * 16 + srow) * 1024 + scol;

    const int xcd = blockIdx.x & 7;
    const int rr  = blockIdx.x >> 3;            // 0..31
    const int tbase = xcd * 250 + rr * 8;
    const int ntile_mine = (rr == 31) ? 2 : 8;  // 31*8+2 = 250 per XCD

    int T  = tbase;
    int bm = T & 15, bn = T >> 4;
    const unsigned short* gA = A  + (size_t)(bm * 256) * 1024 + soff;
    const unsigned short* gB = Bw + (size_t)(bn * 256) * 1024 + soff;

    bf16x8 afr[4][2], b01[2][2], b23[2][2];

    STAGE_A(0, 0, 0, gA); STAGE_A(0, 1, 0, gA);
    STAGE_B(0, 0, 0, gB); STAGE_B(0, 1, 0, gB);
    STAGE_B(1, 0, 1, gB); STAGE_B(1, 1, 1, gB);
    VMCNT4();
    __builtin_amdgcn_s_barrier();

    for (int t = 0; t < ntile_mine; ++t) {
        const bool last = (t == ntile_mine - 1);
        const int Tn = last ? T : T + 1;
        const int bm2 = Tn & 15, bn2 = Tn >> 4;
        const unsigned short* gA2 = A  + (size_t)(bm2 * 256) * 1024 + soff;
        const unsigned short* gB2 = Bw + (size_t)(bn2 * 256) * 1024 + soff;

        f32x4 acc[8][4];
        #pragma unroll
        for (int i = 0; i < 8; ++i)
            #pragma unroll
            for (int j2 = 0; j2 < 4; ++j2) acc[i][j2] = (f32x4){0.f, 0.f, 0.f, 0.f};

        for (int j = 0; j < 8; ++j) {
            const unsigned short* sA = (j == 7) ? gA2 : gA;
            const unsigned short* sB = (j == 7) ? gB2 : gB;
            const int k1 = 2 * j + 1;
            const int k2 = (2 * j + 2) & 15;
            const int k3 = (2 * j + 3) & 15;

            RD_A(0, 0); RD_B(0, 0, b01);
            STAGE_A(1, 0, k1, gA);
            PH_SYNC(); MFMA16(0, 0, b01); PH_END();

            RD_B(0, 2, b23);
            STAGE_A(1, 1, k1, gA);
            PH_SYNC(); MFMA16(0, 2, b23); PH_END();

            RD_A(0, 4);
            STAGE_B(0, 0, k2, sB);
            PH_SYNC(); MFMA16(4, 2, b23); PH_END();

            STAGE_B(0, 1, k2, sB);
            VMCNT4();
            PH_SYNC(); MFMA16(4, 0, b01); PH_END();

            RD_A(1, 0); RD_B(1, 0, b01);
            STAGE_A(0, 0, k2, sA);
            PH_SYNC(); MFMA16(0, 0, b01); PH_END();

            RD_B(1, 2, b23);
            STAGE_A(0, 1, k2, sA);
            PH_SYNC(); MFMA16(0, 2, b23); PH_END();

            RD_A(1, 4);
            STAGE_B(1, 0, k3, sB);
            PH_SYNC(); MFMA16(4, 2, b23); PH_END();

            STAGE_B(1, 1, k3, sB);
            VMCNT4();
            PH_SYNC(); MFMA16(4, 0, b01); PH_END();
        }

        #pragma unroll
        for (int mi = 0; mi < 8; ++mi) {
            const size_t m0 = (size_t)(bm * 256 + wm * 128 + mi * 16 + kg * 4);
            #pragma unroll
            for (int ni = 0; ni < 4; ++ni) {
                const int n = bn * 256 + wn * 64 + ni * 16 + lr;
                float* cp = C + m0 * V_DIM + n;
                cp[0]                 = acc[mi][ni][0];
                cp[(size_t)V_DIM]     = acc[mi][ni][1];
                cp[(size_t)2 * V_DIM] = acc[mi][ni][2];
                cp[(size_t)3 * V_DIM] = acc[mi][ni][3];
            }
        }

        T = Tn; bm = bm2; bn = bn2; gA = gA2; gB = gB2;
    }
}

extern "C" void kernel_launch(void* const* d_in, const int* in_sizes, int n_in,
                              void* d_out, int out_size, void* d_ws, size_t ws_size,
                              hipStream_t stream)
{
    const int*   tokens = (const int*)  d_in[0];
    const float* embedw = (const float*)d_in[1];
    const float* angles = (const float*)d_in[2];
    const float* scales = (const float*)d_in[3];
    const float* shifts = (const float*)d_in[4];
    const float* normw  = (const float*)d_in[5];
    const float* mixw   = (const float*)d_in[6];
    const float* outnw  = (const float*)d_in[7];
    const float* lmhead = (const float*)d_in[8];
    const int*   pi_all = (const int*)  d_in[9];
    const int*   pj_all = (const int*)  d_in[10];
    float* out = (float*)d_out;

    unsigned short* xbf = (unsigned short*)d_ws;               // 8.39 MB
    unsigned short* wbf = xbf + (size_t)NTOK * D_DIM;          // 65.54 MB

    k_chain<<<NTOK / 16, 512, 0, stream>>>(tokens, embedw, angles, scales,
        shifts, normw, mixw, outnw, pi_all, pj_all, lmhead, xbf, wbf);

    k_gemm<<<256, 512, 0, stream>>>(xbf, wbf, out);
}

// Round 9
// 410.916 us; speedup vs baseline: 1.3100x; 1.1386x over previous
//
#include <hip/hip_runtime.h>

#define B_SZ   2
#define S_LEN  2048
#define D_DIM  1024
#define V_DIM  32000
#define NTOK   (B_SZ * S_LEN)   // 4096
#define NCYC   8
#define NPLANES 256
#define EPS_F  1.1920929e-07f
#define NTILE  2000             // 16 bm x 125 bn

typedef float  f32x4  __attribute__((ext_vector_type(4)));
typedef __bf16 bf16x8 __attribute__((ext_vector_type(8)));

__device__ __forceinline__ unsigned short f32_to_bf16(float f) {
    unsigned int u = __builtin_bit_cast(unsigned int, f);
    u += 0x7fffu + ((u >> 16) & 1u);   // round-to-nearest-even
    return (unsigned short)(u >> 16);
}

// ============ fused chain v2: wave-owns-row halo version ===================
// 256 blocks x 512 thr (8 waves). Block owns tokens [t0,t0+16) + 8-halo each
// side = 32 rows in LDS; 8 cycles run locally, valid range shrinks 1/side/cyc
// (proven in round 8). NEW: wave w owns rows 4w..4w+3 entirely; lane owns 16
// cols (4 x float4 at col q*256+ln*4). Row sums = wave-internal shfl_xor
// reduce; same-wave LDS ordering -> only 2 barriers/cycle. m kept in regs.
// lm_head fp32->bf16 slice interleaved per cycle (overlaps BW under compute).
__global__ __launch_bounds__(512, 2) void k_chain(
    const int* __restrict__ tokens, const float* __restrict__ table,
    const float* __restrict__ angles, const float* __restrict__ scales,
    const float* __restrict__ shifts, const float* __restrict__ normw,
    const float* __restrict__ mixw, const float* __restrict__ outnw,
    const int* __restrict__ pi_all, const int* __restrict__ pj_all,
    const float* __restrict__ lmhead,
    unsigned short* __restrict__ xbf, unsigned short* __restrict__ wbf)
{
    __shared__ float lx[32][D_DIM];   // 128 KiB exactly
    const int blk = blockIdx.x, tid = threadIdx.x;
    const int wv = tid >> 6, ln = tid & 63;
    const int t0 = blk << 4;
    const int s0 = t0 & (S_LEN - 1);
    const int seqbase = t0 & ~(S_LEN - 1);
    const int r0 = wv << 2;                    // wave owns rows r0..r0+3

    const float mw0 = mixw[0], mw1 = mixw[1], mw2 = mixw[2];

    // ---- embed owned rows (invalid rows stay 0 = zero padding) ----
    bool valid[4];
    #pragma unroll
    for (int i = 0; i < 4; ++i) {
        const int r = r0 + i;
        const int s = s0 - 8 + r;
        valid[i] = (s >= 0) && (s < S_LEN);
        float4 v0 = make_float4(0.f,0.f,0.f,0.f), v1 = v0, v2 = v0, v3 = v0;
        if (valid[i]) {
            const float* tr = table + (size_t)tokens[seqbase + s] * D_DIM;
            v0 = *(const float4*)(tr +   0 + ln * 4);
            v1 = *(const float4*)(tr + 256 + ln * 4);
            v2 = *(const float4*)(tr + 512 + ln * 4);
            v3 = *(const float4*)(tr + 768 + ln * 4);
        }
        *(float4*)&lx[r][  0 + ln * 4] = v0;
        *(float4*)&lx[r][256 + ln * 4] = v1;
        *(float4*)&lx[r][512 + ln * 4] = v2;
        *(float4*)&lx[r][768 + ln * 4] = v3;
    }
    __syncthreads();

    float4 mreg[4][4];   // [row][q] pre-rotation mix, statically indexed

    for (int c = 0; c < NCYC; ++c) {
        // per-lane params (4 x float4 at owned cols)
        float4 sc[4], sh[4], nw[4];
        #pragma unroll
        for (int q = 0; q < 4; ++q) {
            sc[q] = *(const float4*)(scales + c * D_DIM + q * 256 + ln * 4);
            sh[q] = *(const float4*)(shifts + c * D_DIM + q * 256 + ln * 4);
            nw[q] = *(const float4*)(normw  + c * D_DIM + q * 256 + ln * 4);
        }
        // rotation planes: lane handles planes ln*4..ln*4+3
        int ip[4], jp[4];
        float sa[4], ca[4];
        #pragma unroll
        for (int u = 0; u < 4; ++u) {
            ip[u] = pi_all[c * NPLANES + ln * 4 + u];
            jp[u] = pj_all[c * NPLANES + ln * 4 + u];
            sincosf(angles[c * NPLANES + ln * 4 + u], &sa[u], &ca[u]);
        }

        // ---- mix read (neighbors may belong to other waves) ----
        #pragma unroll
        for (int i = 0; i < 4; ++i) {
            const int r = r0 + i;
            if (r >= c + 1 && r < 31 - c && valid[i]) {
                #pragma unroll
                for (int q = 0; q < 4; ++q) {
                    const float4 a = *(const float4*)&lx[r - 1][q * 256 + ln * 4];
                    const float4 b = *(const float4*)&lx[r    ][q * 256 + ln * 4];
                    const float4 d = *(const float4*)&lx[r + 1][q * 256 + ln * 4];
                    mreg[i][q].x = mw0 * a.x + mw1 * b.x + mw2 * d.x;
                    mreg[i][q].y = mw0 * a.y + mw1 * b.y + mw2 * d.y;
                    mreg[i][q].z = mw0 * a.z + mw1 * b.z + mw2 * d.z;
                    mreg[i][q].w = mw0 * a.w + mw1 * b.w + mw2 * d.w;
                }
            }
        }
        __syncthreads();
        // ---- mix write + rotation + silu/norm/update: all same-wave rows ----
        #pragma unroll
        for (int i = 0; i < 4; ++i) {
            const int r = r0 + i;
            if (r >= c + 1 && r < 31 - c && valid[i]) {
                #pragma unroll
                for (int q = 0; q < 4; ++q)
                    *(float4*)&lx[r][q * 256 + ln * 4] = mreg[i][q];
            }
        }
        // rotation (reads/writes own rows; same-wave LDS ops are ordered)
        #pragma unroll
        for (int i = 0; i < 4; ++i) {
            const int r = r0 + i;
            if (r >= c + 1 && r < 31 - c && valid[i]) {
                float xi[4], xj[4];
                #pragma unroll
                for (int u = 0; u < 4; ++u) { xi[u] = lx[r][ip[u]]; xj[u] = lx[r][jp[u]]; }
                #pragma unroll
                for (int u = 0; u < 4; ++u) {
                    lx[r][ip[u]] = xi[u] * ca[u] - xj[u] * sa[u];
                    lx[r][jp[u]] = xi[u] * sa[u] + xj[u] * ca[u];
                }
            }
        }
        // silu + residual + per-row wave-reduce RMSNorm + writeback
        #pragma unroll
        for (int i = 0; i < 4; ++i) {
            const int r = r0 + i;
            if (r >= c + 1 && r < 31 - c && valid[i]) {
                float4 rr[4];
                float sum = 0.f;
                #pragma unroll
                for (int q = 0; q < 4; ++q) {
                    const float4 xn = *(const float4*)&lx[r][q * 256 + ln * 4];
                    const float a0 = xn.x * sc[q].x + sh[q].x;
                    const float a1 = xn.y * sc[q].y + sh[q].y;
                    const float a2 = xn.z * sc[q].z + sh[q].z;
                    const float a3 = xn.w * sc[q].w + sh[q].w;
                    rr[q].x = a0 / (1.f + expf(-a0)) - mreg[i][q].x;
                    rr[q].y = a1 / (1.f + expf(-a1)) - mreg[i][q].y;
                    rr[q].z = a2 / (1.f + expf(-a2)) - mreg[i][q].z;
                    rr[q].w = a3 / (1.f + expf(-a3)) - mreg[i][q].w;
                    sum += rr[q].x * rr[q].x + rr[q].y * rr[q].y
                         + rr[q].z * rr[q].z + rr[q].w * rr[q].w;
                }
                #pragma unroll
                for (int off = 32; off > 0; off >>= 1)
                    sum += __shfl_xor(sum, off, 64);
                const float inv = rsqrtf(sum * (1.0f / D_DIM) + EPS_F);
                #pragma unroll
                for (int q = 0; q < 4; ++q) {
                    float4 o;
                    o.x = mreg[i][q].x + rr[q].x * inv * nw[q].x;
                    o.y = mreg[i][q].y + rr[q].y * inv * nw[q].y;
                    o.z = mreg[i][q].z + rr[q].z * inv * nw[q].z;
                    o.w = mreg[i][q].w + rr[q].w * inv * nw[q].w;
                    *(float4*)&lx[r][q * 256 + ln * 4] = o;
                }
            }
        }
        // ---- lm_head fp32->bf16 slice for this cycle (overlaps compute) ----
        {
            const int end = (c + 1) * 1024000;
            for (int idx = c * 1024000 + blk * 512 + tid; idx < end; idx += 131072) {
                const float4 v = ((const float4*)lmhead)[idx];
                const ushort4 o = make_ushort4(f32_to_bf16(v.x), f32_to_bf16(v.y),
                                               f32_to_bf16(v.z), f32_to_bf16(v.w));
                ((ushort4*)wbf)[idx] = o;
            }
        }
        __syncthreads();
    }

    // ---- final RMSNorm + bf16 cast; wave w handles rows 8+w and 16+w ----
    float4 ow[4];
    #pragma unroll
    for (int q = 0; q < 4; ++q)
        ow[q] = *(const float4*)(outnw + q * 256 + ln * 4);
    #pragma unroll
    for (int e = 0; e < 2; ++e) {
        const int r = 8 + wv + e * 8;
        float4 v[4];
        float sum = 0.f;
        #pragma unroll
        for (int q = 0; q < 4; ++q) {
            v[q] = *(const float4*)&lx[r][q * 256 + ln * 4];
            sum += v[q].x * v[q].x + v[q].y * v[q].y
                 + v[q].z * v[q].z + v[q].w * v[q].w;
        }
        #pragma unroll
        for (int off = 32; off > 0; off >>= 1)
            sum += __shfl_xor(sum, off, 64);
        const float inv = rsqrtf(sum * (1.0f / D_DIM) + EPS_F);
        unsigned short* xr = xbf + (size_t)(t0 + r - 8) * D_DIM;
        #pragma unroll
        for (int q = 0; q < 4; ++q) {
            const ushort4 o = make_ushort4(f32_to_bf16(v[q].x * inv * ow[q].x),
                                           f32_to_bf16(v[q].y * inv * ow[q].y),
                                           f32_to_bf16(v[q].z * inv * ow[q].z),
                                           f32_to_bf16(v[q].w * inv * ow[q].w));
            *(ushort4*)(xr + q * 256 + ln * 4) = o;
        }
    }
}

// ====== persistent GEMM: 256x256 tile, BK=64, 8-phase, XCD-grouped tiles ===
// (unchanged -- best measured ~300 us)
#define GLD_LDS(g, l)                                                          \
    __builtin_amdgcn_global_load_lds(                                          \
        (const __attribute__((address_space(1))) void*)(g),                    \
        (__attribute__((address_space(3))) void*)(l), 16, 0, 0)

#define STAGE_A(BUF, H, KT, P) do {                                            \
    GLD_LDS((P) + (size_t)(H) * 131072 + (size_t)(KT) * 64,                    \
            &lds[(BUF) * 32768 + (H) * 8192 + wave * 1024]);                   \
    GLD_LDS((P) + (size_t)(H) * 131072 + 8192 + (size_t)(KT) * 64,             \
            &lds[(BUF) * 32768 + (H) * 8192 + wave * 1024 + 512]);             \
} while (0)

#define STAGE_B(BUF, H, KT, P) do {                                            \
    GLD_LDS((P) + (size_t)(H) * 131072 + (size_t)(KT) * 64,                    \
            &lds[16384 + (BUF) * 32768 + (H) * 8192 + wave * 1024]);           \
    GLD_LDS((P) + (size_t)(H) * 131072 + 8192 + (size_t)(KT) * 64,             \
            &lds[16384 + (BUF) * 32768 + (H) * 8192 + wave * 1024 + 512]);     \
} while (0)

#define RD_A(BUF, MIB) do { _Pragma("unroll")                                  \
    for (int q_ = 0; q_ < 4; ++q_) {                                           \
        afr[q_][0] = *(const bf16x8*)&lds[(BUF) * 32768 + aoff + ((MIB) + q_) * 1024 + kx0]; \
        afr[q_][1] = *(const bf16x8*)&lds[(BUF) * 32768 + aoff + ((MIB) + q_) * 1024 + kx1]; \
    } } while (0)

#define RD_B(BUF, NIB, DST) do { _Pragma("unroll")                             \
    for (int n_ = 0; n_ < 2; ++n_) {                                           \
        DST[n_][0] = *(const bf16x8*)&lds[(BUF) * 32768 + boff + ((NIB) + n_) * 1024 + kx0]; \
        DST[n_][1] = *(const bf16x8*)&lds[(BUF) * 32768 + boff + ((NIB) + n_) * 1024 + kx1]; \
    } } while (0)

#define MFMA16(MIB, NIB, BF) do {                                              \
    __builtin_amdgcn_s_setprio(1);                                             \
    _Pragma("unroll") for (int m_ = 0; m_ < 4; ++m_)                           \
    _Pragma("unroll") for (int n_ = 0; n_ < 2; ++n_) {                         \
        acc[(MIB) + m_][(NIB) + n_] = __builtin_amdgcn_mfma_f32_16x16x32_bf16( \
            afr[m_][0], BF[n_][0], acc[(MIB) + m_][(NIB) + n_], 0, 0, 0);      \
        acc[(MIB) + m_][(NIB) + n_] = __builtin_amdgcn_mfma_f32_16x16x32_bf16( \
            afr[m_][1], BF[n_][1], acc[(MIB) + m_][(NIB) + n_], 0, 0, 0);      \
    }                                                                          \
    __builtin_amdgcn_s_setprio(0); } while (0)

#define PH_SYNC() do { __builtin_amdgcn_s_barrier();                           \
    asm volatile("s_waitcnt lgkmcnt(0)" ::: "memory"); } while (0)
#define PH_END() do { asm volatile("" ::: "memory");                           \
    __builtin_amdgcn_s_barrier(); } while (0)
#define VMCNT4() asm volatile("s_waitcnt vmcnt(4)" ::: "memory")

__global__ __launch_bounds__(512, 2) void k_gemm(
    const unsigned short* __restrict__ A,   // [NTOK, 1024] bf16 bits
    const unsigned short* __restrict__ Bw,  // [V, 1024]    bf16 bits
    float* __restrict__ C)                  // [NTOK, V]    fp32
{
    __shared__ __align__(16) unsigned short lds[65536];   // 128 KiB
    const int tid = threadIdx.x;
    const int wave = tid >> 6, lane = tid & 63;
    const int wm = wave >> 2, wn = wave & 3;
    const int lr = lane & 15, kg = lane >> 4;

    const int xr  = (lane & 7) * 8;
    const int kx0 = (kg * 8) ^ xr;
    const int kx1 = (32 + kg * 8) ^ xr;
    const int aoff = (wm * 128 + lr) * 64;
    const int boff = 16384 + (wn * 64 + lr) * 64;

    const int srow = lane >> 3;
    const int scol = ((lane & 7) ^ srow) * 8;   // pre-swizzled source col
    const int soff = (wave * 16 + srow) * 1024 + scol;

    const int xcd = blockIdx.x & 7;
    const int rr  = blockIdx.x >> 3;            // 0..31
    const int tbase = xcd * 250 + rr * 8;
    const int ntile_mine = (rr == 31) ? 2 : 8;  // 31*8+2 = 250 per XCD

    int T  = tbase;
    int bm = T & 15, bn = T >> 4;
    const unsigned short* gA = A  + (size_t)(bm * 256) * 1024 + soff;
    const unsigned short* gB = Bw + (size_t)(bn * 256) * 1024 + soff;

    bf16x8 afr[4][2], b01[2][2], b23[2][2];

    STAGE_A(0, 0, 0, gA); STAGE_A(0, 1, 0, gA);
    STAGE_B(0, 0, 0, gB); STAGE_B(0, 1, 0, gB);
    STAGE_B(1, 0, 1, gB); STAGE_B(1, 1, 1, gB);
    VMCNT4();
    __builtin_amdgcn_s_barrier();

    for (int t = 0; t < ntile_mine; ++t) {
        const bool last = (t == ntile_mine - 1);
        const int Tn = last ? T : T + 1;
        const int bm2 = Tn & 15, bn2 = Tn >> 4;
        const unsigned short* gA2 = A  + (size_t)(bm2 * 256) * 1024 + soff;
        const unsigned short* gB2 = Bw + (size_t)(bn2 * 256) * 1024 + soff;

        f32x4 acc[8][4];
        #pragma unroll
        for (int i = 0; i < 8; ++i)
            #pragma unroll
            for (int j2 = 0; j2 < 4; ++j2) acc[i][j2] = (f32x4){0.f, 0.f, 0.f, 0.f};

        for (int j = 0; j < 8; ++j) {
            const unsigned short* sA = (j == 7) ? gA2 : gA;
            const unsigned short* sB = (j == 7) ? gB2 : gB;
            const int k1 = 2 * j + 1;
            const int k2 = (2 * j + 2) & 15;
            const int k3 = (2 * j + 3) & 15;

            RD_A(0, 0); RD_B(0, 0, b01);
            STAGE_A(1, 0, k1, gA);
            PH_SYNC(); MFMA16(0, 0, b01); PH_END();

            RD_B(0, 2, b23);
            STAGE_A(1, 1, k1, gA);
            PH_SYNC(); MFMA16(0, 2, b23); PH_END();

            RD_A(0, 4);
            STAGE_B(0, 0, k2, sB);
            PH_SYNC(); MFMA16(4, 2, b23); PH_END();

            STAGE_B(0, 1, k2, sB);
            VMCNT4();
            PH_SYNC(); MFMA16(4, 0, b01); PH_END();

            RD_A(1, 0); RD_B(1, 0, b01);
            STAGE_A(0, 0, k2, sA);
            PH_SYNC(); MFMA16(0, 0, b01); PH_END();

            RD_B(1, 2, b23);
            STAGE_A(0, 1, k2, sA);
            PH_SYNC(); MFMA16(0, 2, b23); PH_END();

            RD_A(1, 4);
            STAGE_B(1, 0, k3, sB);
            PH_SYNC(); MFMA16(4, 2, b23); PH_END();

            STAGE_B(1, 1, k3, sB);
            VMCNT4();
            PH_SYNC(); MFMA16(4, 0, b01); PH_END();
        }

        #pragma unroll
        for (int mi = 0; mi < 8; ++mi) {
            const size_t m0 = (size_t)(bm * 256 + wm * 128 + mi * 16 + kg * 4);
            #pragma unroll
            for (int ni = 0; ni < 4; ++ni) {
                const int n = bn * 256 + wn * 64 + ni * 16 + lr;
                float* cp = C + m0 * V_DIM + n;
                cp[0]                 = acc[mi][ni][0];
                cp[(size_t)V_DIM]     = acc[mi][ni][1];
                cp[(size_t)2 * V_DIM] = acc[mi][ni][2];
                cp[(size_t)3 * V_DIM] = acc[mi][ni][3];
            }
        }

        T = Tn; bm = bm2; bn = bn2; gA = gA2; gB = gB2;
    }
}

extern "C" void kernel_launch(void* const* d_in, const int* in_sizes, int n_in,
                              void* d_out, int out_size, void* d_ws, size_t ws_size,
                              hipStream_t stream)
{
    const int*   tokens = (const int*)  d_in[0];
    const float* embedw = (const float*)d_in[1];
    const float* angles = (const float*)d_in[2];
    const float* scales = (const float*)d_in[3];
    const float* shifts = (const float*)d_in[4];
    const float* normw  = (const float*)d_in[5];
    const float* mixw   = (const float*)d_in[6];
    const float* outnw  = (const float*)d_in[7];
    const float* lmhead = (const float*)d_in[8];
    const int*   pi_all = (const int*)  d_in[9];
    const int*   pj_all = (const int*)  d_in[10];
    float* out = (float*)d_out;

    unsigned short* xbf = (unsigned short*)d_ws;               // 8.39 MB
    unsigned short* wbf = xbf + (size_t)NTOK * D_DIM;          // 65.54 MB

    k_chain<<<NTOK / 16, 512, 0, stream>>>(tokens, embedw, angles, scales,
        shifts, normw, mixw, outnw, pi_all, pj_all, lmhead, xbf, wbf);

    k_gemm<<<256, 512, 0, stream>>>(xbf, wbf, out);
}